// Round 1
// baseline (3258.075 us; speedup 1.0000x reference)
//
#include <hip/hip_runtime.h>
#include <cmath>

#define NU 100000
#define NI 50000
#define NALL 150000
#define DIM 64
#define NE 4800000

// ---------- kernels ----------

__global__ void concat_init_kernel(const float* __restrict__ u, const float* __restrict__ it,
                                   float* __restrict__ w0, float* __restrict__ out) {
    int idx = blockIdx.x * blockDim.x + threadIdx.x;
    const int total = NALL * DIM;
    if (idx >= total) return;
    const int nue = NU * DIM;
    float v = (idx < nue) ? u[idx] : it[idx - nue];
    w0[idx] = v;
    int row = idx >> 6, d = idx & 63;
    out[(size_t)row * 128 + d] = v;   // sum := e0  (fresh overwrite each launch)
}

// One edge per 64-lane wave; lane = dim. Gather + scatter both coalesced 256B.
__global__ void spmm_kernel(const int* __restrict__ rows, const int* __restrict__ cols,
                            const float* __restrict__ vals, const float* __restrict__ x,
                            float* __restrict__ y) {
    int gid = blockIdx.x * blockDim.x + threadIdx.x;
    int e = gid >> 6;
    if (e >= NE) return;
    int lane = threadIdx.x & 63;
    int r = rows[e], c = cols[e];
    float v = vals[e];
    float xv = x[(size_t)c * DIM + lane];
    atomicAdd(&y[(size_t)r * DIM + lane], v * xv);
}

// t (in) holds spmm result; overwritten with e_k = t1*t + t2*e_{k-1} - t3*e_{k-2}.
// Running band-stop sum accumulated into out (stride 128).
__global__ void combine3_kernel(float* __restrict__ t, const float* __restrict__ ekm1,
                                const float* __restrict__ ekm2, float t1, float t2, float t3,
                                float* __restrict__ out) {
    int idx = blockIdx.x * blockDim.x + threadIdx.x;
    const int total = NALL * DIM;
    if (idx >= total) return;
    float ek = t1 * t[idx] + t2 * ekm1[idx] - t3 * ekm2[idx];
    t[idx] = ek;
    int row = idx >> 6, d = idx & 63;
    out[(size_t)row * 128 + d] += ek;
}

__global__ void finalize_kernel(const float* __restrict__ u, const float* __restrict__ it,
                                float* __restrict__ out) {
    int idx = blockIdx.x * blockDim.x + threadIdx.x;
    const int total = NALL * DIM;
    if (idx >= total) return;
    const int nue = NU * DIM;
    float v = (idx < nue) ? u[idx] : it[idx - nue];  // embed re-derived from inputs
    int row = idx >> 6, d = idx & 63;
    size_t o = (size_t)row * 128 + d;
    float bs = out[o] * 0.25f;                 // mean over 4 layers
    float bp = tanhf(0.1f * v - bs);           // ALPHA = 0.1
    out[o] = bs;
    out[o + DIM] = bp;
}

// ---------- launch ----------

extern "C" void kernel_launch(void* const* d_in, const int* in_sizes, int n_in,
                              void* d_out, int out_size, void* d_ws, size_t ws_size,
                              hipStream_t stream) {
    const float* user_emb = (const float*)d_in[0];
    const float* item_emb = (const float*)d_in[1];
    const int*   rows     = (const int*)d_in[2];
    const int*   cols     = (const int*)d_in[3];
    const float* vals     = (const float*)d_in[4];
    float* out = (float*)d_out;

    size_t nbuf = (size_t)NALL * DIM;       // 9.6M floats = 38.4 MB
    float* W0 = (float*)d_ws;
    float* W1 = W0 + nbuf;
    float* W2 = W1 + nbuf;

    // Jacobi polynomial coefficients (general in A,B; here A=B=1)
    const double A = 1.0, B = 1.0, ab = A + B;
    float c0 = (float)((A - B) / 2.0);
    float c1 = (float)((A + B) / 2.0);
    float th1[4], th2[4], th3[4];
    for (int k = 2; k <= 3; k++) {
        th1[k] = (float)((2.0*k+ab)*(2.0*k+ab-1.0)/((k+ab)*2.0*k));
        th2[k] = (float)((2.0*k+ab-1.0)*(A*A-B*B)/((2.0*k+ab-2.0)*(k+ab)*2.0*k));
        th3[k] = (float)((k+A-1.0)*(k+B-1.0)*(2.0*k+ab)/(k*(ab+k)*(2.0*k+ab-2.0)));
    }

    const int total = NALL * DIM;
    dim3 blk(256);
    dim3 grdE((total + 255) / 256);
    long long spmm_threads = (long long)NE * 64;
    dim3 grdS((unsigned)((spmm_threads + 255) / 256));

    // e0
    concat_init_kernel<<<grdE, blk, 0, stream>>>(user_emb, item_emb, W0, out);

    // e1 = c0*e0 + c1*spmm(e0)
    hipMemsetAsync(W1, 0, nbuf * sizeof(float), stream);
    spmm_kernel<<<grdS, blk, 0, stream>>>(rows, cols, vals, W0, W1);
    combine3_kernel<<<grdE, blk, 0, stream>>>(W1, W0, W0, c1, c0, 0.0f, out);

    // e2 = th1*spmm(e1) + th2*e1 - th3*e0
    hipMemsetAsync(W2, 0, nbuf * sizeof(float), stream);
    spmm_kernel<<<grdS, blk, 0, stream>>>(rows, cols, vals, W1, W2);
    combine3_kernel<<<grdE, blk, 0, stream>>>(W2, W1, W0, th1[2], th2[2], th3[2], out);

    // e3 = th1*spmm(e2) + th2*e2 - th3*e1   (e0's buffer recycled)
    hipMemsetAsync(W0, 0, nbuf * sizeof(float), stream);
    spmm_kernel<<<grdS, blk, 0, stream>>>(rows, cols, vals, W2, W0);
    combine3_kernel<<<grdE, blk, 0, stream>>>(W0, W2, W1, th1[3], th2[3], th3[3], out);

    // band_stop = sum/4 ; band_pass = tanh(alpha*embed - band_stop)
    finalize_kernel<<<grdE, blk, 0, stream>>>(user_emb, item_emb, out);
}

// Round 2
// 1314.350 us; speedup vs baseline: 2.4788x; 2.4788x over previous
//
#include <hip/hip_runtime.h>
#include <cmath>

#define NU 100000
#define NI 50000
#define NALL 150000
#define DIM 64
#define NE 4800000

// ---------------- CSR build ----------------

__global__ void hist_kernel(const int* __restrict__ rows, int* __restrict__ counts) {
    int e = blockIdx.x * blockDim.x + threadIdx.x;
    if (e < NE) atomicAdd(&counts[rows[e]], 1);
}

// Single-block exclusive scan of counts[NALL] -> row_ptr[NALL+1]
__global__ void scan_kernel(const int* __restrict__ counts, int* __restrict__ row_ptr) {
    __shared__ int ssum[1024];
    int t = threadIdx.x;
    const int chunk = (NALL + 1023) / 1024;           // 147
    int lo = t * chunk, hi = lo + chunk;
    if (hi > NALL) hi = NALL;
    int s = 0;
    for (int i = lo; i < hi; ++i) s += counts[i];
    ssum[t] = s;
    __syncthreads();
    for (int off = 1; off < 1024; off <<= 1) {        // Hillis-Steele inclusive
        int v = (t >= off) ? ssum[t - off] : 0;
        __syncthreads();
        ssum[t] += v;
        __syncthreads();
    }
    int run = ssum[t] - s;                            // exclusive prefix
    for (int i = lo; i < hi; ++i) { row_ptr[i] = run; run += counts[i]; }
    if (t == 1023) row_ptr[NALL] = ssum[1023];
}

__global__ void scatter_kernel(const int* __restrict__ rows, const int* __restrict__ cols,
                               const float* __restrict__ vals, const int* __restrict__ row_ptr,
                               int* __restrict__ fill, int2* __restrict__ sedges) {
    int e = blockIdx.x * blockDim.x + threadIdx.x;
    if (e >= NE) return;
    int r = rows[e];
    int pos = row_ptr[r] + atomicAdd(&fill[r], 1);
    sedges[pos] = make_int2(cols[e], __float_as_int(vals[e]));
}

// ---------------- embedding passes ----------------

__global__ void concat_init_kernel(const float* __restrict__ u, const float* __restrict__ it,
                                   float* __restrict__ w0, float* __restrict__ out) {
    int idx = blockIdx.x * blockDim.x + threadIdx.x;
    const int total = NALL * DIM;
    if (idx >= total) return;
    const int nue = NU * DIM;
    float v = (idx < nue) ? u[idx] : it[idx - nue];
    w0[idx] = v;
    int row = idx >> 6, d = idx & 63;
    out[(size_t)row * 128 + d] = v;   // running band-stop sum := e0
}

// One wave per row: acc[lane] = sum_e val*x[col][lane]; fused Jacobi combine + sum update.
__global__ void spmm_combine_kernel(const int* __restrict__ row_ptr,
                                    const int2* __restrict__ sedges,
                                    const float* __restrict__ x,
                                    const float* __restrict__ ekm1,
                                    const float* __restrict__ ekm2,
                                    float t1, float t2, float t3,
                                    float* __restrict__ ek_out,
                                    float* __restrict__ out) {
    int wid = (blockIdx.x * blockDim.x + threadIdx.x) >> 6;
    if (wid >= NALL) return;
    int lane = threadIdx.x & 63;
    int s = row_ptr[wid], e = row_ptr[wid + 1];
    float acc = 0.f;
    #pragma unroll 4
    for (int i = s; i < e; ++i) {
        int2 ed = sedges[i];
        acc += __int_as_float(ed.y) * x[(size_t)ed.x * DIM + lane];
    }
    size_t o = (size_t)wid * DIM + lane;
    float ek = t1 * acc + t2 * ekm1[o] - t3 * ekm2[o];
    ek_out[o] = ek;
    out[(size_t)wid * 128 + lane] += ek;
}

__global__ void finalize_kernel(const float* __restrict__ u, const float* __restrict__ it,
                                float* __restrict__ out) {
    int idx = blockIdx.x * blockDim.x + threadIdx.x;
    const int total = NALL * DIM;
    if (idx >= total) return;
    const int nue = NU * DIM;
    float v = (idx < nue) ? u[idx] : it[idx - nue];
    int row = idx >> 6, d = idx & 63;
    size_t o = (size_t)row * 128 + d;
    float bs = out[o] * 0.25f;
    float bp = tanhf(0.1f * v - bs);
    out[o] = bs;
    out[o + DIM] = bp;
}

// ---------------- fallback (atomic scatter) ----------------

__global__ void spmm_atomic_kernel(const int* __restrict__ rows, const int* __restrict__ cols,
                                   const float* __restrict__ vals, const float* __restrict__ x,
                                   float* __restrict__ y) {
    int gid = blockIdx.x * blockDim.x + threadIdx.x;
    int e = gid >> 6;
    if (e >= NE) return;
    int lane = threadIdx.x & 63;
    atomicAdd(&y[(size_t)rows[e] * DIM + lane], vals[e] * x[(size_t)cols[e] * DIM + lane]);
}

__global__ void combine3_kernel(float* __restrict__ t, const float* __restrict__ ekm1,
                                const float* __restrict__ ekm2, float t1, float t2, float t3,
                                float* __restrict__ out) {
    int idx = blockIdx.x * blockDim.x + threadIdx.x;
    const int total = NALL * DIM;
    if (idx >= total) return;
    float ek = t1 * t[idx] + t2 * ekm1[idx] - t3 * ekm2[idx];
    t[idx] = ek;
    int row = idx >> 6, d = idx & 63;
    out[(size_t)row * 128 + d] += ek;
}

// ---------------- launch ----------------

extern "C" void kernel_launch(void* const* d_in, const int* in_sizes, int n_in,
                              void* d_out, int out_size, void* d_ws, size_t ws_size,
                              hipStream_t stream) {
    const float* user_emb = (const float*)d_in[0];
    const float* item_emb = (const float*)d_in[1];
    const int*   rows     = (const int*)d_in[2];
    const int*   cols     = (const int*)d_in[3];
    const float* vals     = (const float*)d_in[4];
    float* out = (float*)d_out;

    const size_t nbuf = (size_t)NALL * DIM;            // 9.6M floats
    float* W0 = (float*)d_ws;
    float* W1 = W0 + nbuf;
    float* W2 = W1 + nbuf;
    int2*  sedges  = (int2*)(W2 + nbuf);               // NE * 8 B
    int*   row_ptr = (int*)(sedges + NE);              // NALL+1
    int*   counts  = row_ptr + (NALL + 1);             // NALL
    int*   fill    = counts + NALL;                    // NALL
    size_t need = (size_t)(fill + NALL) - (size_t)d_ws;

    // Jacobi coefficients (A=B=1 here, computed generically)
    const double A = 1.0, B = 1.0, ab = A + B;
    float c0 = (float)((A - B) / 2.0);
    float c1 = (float)((A + B) / 2.0);
    float th1[4], th2[4], th3[4];
    for (int k = 2; k <= 3; k++) {
        th1[k] = (float)((2.0*k+ab)*(2.0*k+ab-1.0)/((k+ab)*2.0*k));
        th2[k] = (float)((2.0*k+ab-1.0)*(A*A-B*B)/((2.0*k+ab-2.0)*(k+ab)*2.0*k));
        th3[k] = (float)((k+A-1.0)*(k+B-1.0)*(2.0*k+ab)/(k*(ab+k)*(2.0*k+ab-2.0)));
    }

    const int total = NALL * DIM;
    dim3 blk(256);
    dim3 grdE((total + 255) / 256);                    // elementwise over 9.6M
    dim3 grdEdge((NE + 255) / 256);                    // per-edge
    dim3 grdRow((NALL * 64 + 255) / 256);              // wave-per-row

    if (ws_size >= need) {
        // ---- CSR build (once per launch, reused by 3 SpMMs) ----
        hipMemsetAsync(counts, 0, NALL * sizeof(int), stream);
        hipMemsetAsync(fill, 0, NALL * sizeof(int), stream);
        hist_kernel<<<grdEdge, blk, 0, stream>>>(rows, counts);
        scan_kernel<<<1, 1024, 0, stream>>>(counts, row_ptr);
        scatter_kernel<<<grdEdge, blk, 0, stream>>>(rows, cols, vals, row_ptr, fill, sedges);

        // ---- propagation ----
        concat_init_kernel<<<grdE, blk, 0, stream>>>(user_emb, item_emb, W0, out);
        spmm_combine_kernel<<<grdRow, blk, 0, stream>>>(row_ptr, sedges, W0, W0, W0,
                                                        c1, c0, 0.0f, W1, out);
        spmm_combine_kernel<<<grdRow, blk, 0, stream>>>(row_ptr, sedges, W1, W1, W0,
                                                        th1[2], th2[2], th3[2], W2, out);
        spmm_combine_kernel<<<grdRow, blk, 0, stream>>>(row_ptr, sedges, W2, W2, W1,
                                                        th1[3], th2[3], th3[3], W0, out);
        finalize_kernel<<<grdE, blk, 0, stream>>>(user_emb, item_emb, out);
    } else {
        // ---- fallback: round-1 atomic path ----
        long long spmm_threads = (long long)NE * 64;
        dim3 grdS((unsigned)((spmm_threads + 255) / 256));
        concat_init_kernel<<<grdE, blk, 0, stream>>>(user_emb, item_emb, W0, out);
        hipMemsetAsync(W1, 0, nbuf * sizeof(float), stream);
        spmm_atomic_kernel<<<grdS, blk, 0, stream>>>(rows, cols, vals, W0, W1);
        combine3_kernel<<<grdE, blk, 0, stream>>>(W1, W0, W0, c1, c0, 0.0f, out);
        hipMemsetAsync(W2, 0, nbuf * sizeof(float), stream);
        spmm_atomic_kernel<<<grdS, blk, 0, stream>>>(rows, cols, vals, W1, W2);
        combine3_kernel<<<grdE, blk, 0, stream>>>(W2, W1, W0, th1[2], th2[2], th3[2], out);
        hipMemsetAsync(W0, 0, nbuf * sizeof(float), stream);
        spmm_atomic_kernel<<<grdS, blk, 0, stream>>>(rows, cols, vals, W2, W0);
        combine3_kernel<<<grdE, blk, 0, stream>>>(W0, W2, W1, th1[3], th2[3], th3[3], out);
        finalize_kernel<<<grdE, blk, 0, stream>>>(user_emb, item_emb, out);
    }
}

// Round 3
// 885.657 us; speedup vs baseline: 3.6787x; 1.4840x over previous
//
#include <hip/hip_runtime.h>
#include <cmath>

#define NU 100000
#define NI 50000
#define NALL 150000
#define DIM 64
#define NE 4800000

#define BSH 7                 // bucket = row >> 7  (128 rows/bucket)
#define BROWS 128
#define NBUCK ((NALL + BROWS - 1) / BROWS)   // 1172
#define EPT 16
#define CHUNK (256 * EPT)     // 4096 edges per binning block
#define COLMASK 0x3FFFF       // 18 bits, NALL < 2^18

// ---------------- CSR build (hierarchical) ----------------

__global__ void bucket_hist_kernel(const int* __restrict__ rows, int* __restrict__ bcnt) {
    __shared__ int h[NBUCK];
    for (int i = threadIdx.x; i < NBUCK; i += 256) h[i] = 0;
    __syncthreads();
    int base = blockIdx.x * CHUNK;
    #pragma unroll
    for (int i = 0; i < EPT; i++) {
        int e = base + threadIdx.x + i * 256;
        if (e < NE) atomicAdd(&h[rows[e] >> BSH], 1);
    }
    __syncthreads();
    for (int i = threadIdx.x; i < NBUCK; i += 256)
        if (h[i]) atomicAdd(&bcnt[i], h[i]);
}

__global__ void bucket_scan_kernel(const int* __restrict__ bcnt, int* __restrict__ bptr) {
    __shared__ int s[1024];
    int t = threadIdx.x;
    const int chunk = (NBUCK + 1023) / 1024;   // 2
    int lo = t * chunk, hi = lo + chunk;
    if (hi > NBUCK) hi = NBUCK;
    int sum = 0;
    for (int i = lo; i < hi; ++i) sum += bcnt[i];
    s[t] = sum;
    __syncthreads();
    for (int off = 1; off < 1024; off <<= 1) {
        int v = (t >= off) ? s[t - off] : 0;
        __syncthreads();
        s[t] += v;
        __syncthreads();
    }
    int run = s[t] - sum;
    for (int i = lo; i < hi; ++i) { bptr[i] = run; run += bcnt[i]; }
    if (t == 1023) bptr[NBUCK] = s[1023];
}

// Coarse scatter: group edges by bucket in LDS, append grouped runs to bucket regions.
__global__ void binned_scatter_kernel(const int* __restrict__ rows, const int* __restrict__ cols,
                                      const float* __restrict__ vals, const int* __restrict__ bptr,
                                      int* __restrict__ bfill, int2* __restrict__ tmp) {
    __shared__ int lcnt[NBUCK];
    __shared__ int lbase[NBUCK];
    for (int i = threadIdx.x; i < NBUCK; i += 256) lcnt[i] = 0;
    __syncthreads();
    int base = blockIdx.x * CHUNK;
    int bk[EPT], rk[EPT];
    #pragma unroll
    for (int i = 0; i < EPT; i++) {
        int e = base + threadIdx.x + i * 256;
        if (e < NE) {
            bk[i] = rows[e] >> BSH;
            rk[i] = atomicAdd(&lcnt[bk[i]], 1);
        } else bk[i] = -1;
    }
    __syncthreads();
    for (int i = threadIdx.x; i < NBUCK; i += 256) {
        int c = lcnt[i];
        lbase[i] = c ? atomicAdd(&bfill[i], c) : 0;
    }
    __syncthreads();
    #pragma unroll
    for (int i = 0; i < EPT; i++) {
        int e = base + threadIdx.x + i * 256;
        if (e < NE) {
            int r = rows[e];
            int key = ((r & (BROWS - 1)) << 18) | cols[e];
            tmp[bptr[bk[i]] + lbase[bk[i]] + rk[i]] = make_int2(key, __float_as_int(vals[e]));
        }
    }
}

// Exact within-bucket counting sort (one block per bucket); emits row_ptr.
__global__ void bucket_sort_kernel(const int* __restrict__ bptr, const int2* __restrict__ tmp,
                                   int2* __restrict__ sedges, int* __restrict__ row_ptr) {
    __shared__ int h[BROWS], f[BROWS], sc[BROWS];
    int b = blockIdx.x, t = threadIdx.x;
    int s0 = bptr[b], s1 = bptr[b + 1];
    if (t < BROWS) { h[t] = 0; f[t] = 0; }
    __syncthreads();
    for (int i = s0 + t; i < s1; i += 256) atomicAdd(&h[tmp[i].x >> 18], 1);
    __syncthreads();
    if (t < BROWS) sc[t] = h[t];
    __syncthreads();
    for (int off = 1; off < BROWS; off <<= 1) {
        int v = 0;
        if (t < BROWS && t >= off) v = sc[t - off];
        __syncthreads();
        if (t < BROWS) sc[t] += v;
        __syncthreads();
    }
    if (t < BROWS) {
        int row = b * BROWS + t;
        if (row < NALL) row_ptr[row] = s0 + sc[t] - h[t];
    }
    if (b == NBUCK - 1 && t == 0) row_ptr[NALL] = s1;
    __syncthreads();
    for (int i = s0 + t; i < s1; i += 256) {
        int2 ed = tmp[i];
        int rl = ed.x >> 18;
        int r = atomicAdd(&f[rl], 1);
        sedges[s0 + sc[rl] - h[rl] + r] = ed;
    }
}

// ---------------- embedding passes ----------------

__global__ void concat_init_kernel(const float* __restrict__ u, const float* __restrict__ it,
                                   float* __restrict__ w0, float* __restrict__ out) {
    int idx = blockIdx.x * blockDim.x + threadIdx.x;
    const int total = NALL * DIM;
    if (idx >= total) return;
    const int nue = NU * DIM;
    float v = (idx < nue) ? u[idx] : it[idx - nue];
    w0[idx] = v;
    int row = idx >> 6, d = idx & 63;
    out[(size_t)row * 128 + d] = v;   // running band-stop sum := e0
}

// One wave per row: register accumulate; fused Jacobi combine + band-stop sum update.
__global__ void spmm_combine_kernel(const int* __restrict__ row_ptr,
                                    const int2* __restrict__ sedges,
                                    const float* __restrict__ x,
                                    const float* __restrict__ ekm1,
                                    const float* __restrict__ ekm2,
                                    float t1, float t2, float t3,
                                    float* __restrict__ ek_out,
                                    float* __restrict__ out) {
    int wid = (blockIdx.x * blockDim.x + threadIdx.x) >> 6;
    if (wid >= NALL) return;
    int lane = threadIdx.x & 63;
    int s = row_ptr[wid], e = row_ptr[wid + 1];
    float acc = 0.f;
    #pragma unroll 4
    for (int i = s; i < e; ++i) {
        int2 ed = sedges[i];
        acc += __int_as_float(ed.y) * x[(size_t)(ed.x & COLMASK) * DIM + lane];
    }
    size_t o = (size_t)wid * DIM + lane;
    float ek = t1 * acc + t2 * ekm1[o] - t3 * ekm2[o];
    ek_out[o] = ek;
    out[(size_t)wid * 128 + lane] += ek;
}

__global__ void finalize_kernel(const float* __restrict__ u, const float* __restrict__ it,
                                float* __restrict__ out) {
    int idx = blockIdx.x * blockDim.x + threadIdx.x;
    const int total = NALL * DIM;
    if (idx >= total) return;
    const int nue = NU * DIM;
    float v = (idx < nue) ? u[idx] : it[idx - nue];
    int row = idx >> 6, d = idx & 63;
    size_t o = (size_t)row * 128 + d;
    float bs = out[o] * 0.25f;
    float bp = tanhf(0.1f * v - bs);
    out[o] = bs;
    out[o + DIM] = bp;
}

// ---------------- fallback (atomic scatter) ----------------

__global__ void spmm_atomic_kernel(const int* __restrict__ rows, const int* __restrict__ cols,
                                   const float* __restrict__ vals, const float* __restrict__ x,
                                   float* __restrict__ y) {
    int gid = blockIdx.x * blockDim.x + threadIdx.x;
    int e = gid >> 6;
    if (e >= NE) return;
    int lane = threadIdx.x & 63;
    atomicAdd(&y[(size_t)rows[e] * DIM + lane], vals[e] * x[(size_t)cols[e] * DIM + lane]);
}

__global__ void combine3_kernel(float* __restrict__ t, const float* __restrict__ ekm1,
                                const float* __restrict__ ekm2, float t1, float t2, float t3,
                                float* __restrict__ out) {
    int idx = blockIdx.x * blockDim.x + threadIdx.x;
    const int total = NALL * DIM;
    if (idx >= total) return;
    float ek = t1 * t[idx] + t2 * ekm1[idx] - t3 * ekm2[idx];
    t[idx] = ek;
    int row = idx >> 6, d = idx & 63;
    out[(size_t)row * 128 + d] += ek;
}

// ---------------- launch ----------------

extern "C" void kernel_launch(void* const* d_in, const int* in_sizes, int n_in,
                              void* d_out, int out_size, void* d_ws, size_t ws_size,
                              hipStream_t stream) {
    const float* user_emb = (const float*)d_in[0];
    const float* item_emb = (const float*)d_in[1];
    const int*   rows     = (const int*)d_in[2];
    const int*   cols     = (const int*)d_in[3];
    const float* vals     = (const float*)d_in[4];
    float* out = (float*)d_out;

    const size_t nbuf = (size_t)NALL * DIM;            // 9.6M floats = 38.4 MB
    float* W0 = (float*)d_ws;
    float* W1 = W0 + nbuf;
    float* W2 = W1 + nbuf;
    int2*  tmp     = (int2*)W1;                        // alias: used only before propagation
    int2*  sedges  = (int2*)(W2 + nbuf);               // NE * 8 B
    int*   row_ptr = (int*)(sedges + NE);              // NALL+1
    int*   bcnt    = row_ptr + (NALL + 1);             // NBUCK
    int*   bptr    = bcnt + NBUCK;                     // NBUCK+1
    int*   bfill   = bptr + (NBUCK + 1);               // NBUCK
    size_t need = (size_t)((char*)(bfill + NBUCK) - (char*)d_ws);

    // Jacobi coefficients (A=B=1 here, computed generically)
    const double A = 1.0, B = 1.0, ab = A + B;
    float c0 = (float)((A - B) / 2.0);
    float c1 = (float)((A + B) / 2.0);
    float th1[4], th2[4], th3[4];
    for (int k = 2; k <= 3; k++) {
        th1[k] = (float)((2.0*k+ab)*(2.0*k+ab-1.0)/((k+ab)*2.0*k));
        th2[k] = (float)((2.0*k+ab-1.0)*(A*A-B*B)/((2.0*k+ab-2.0)*(k+ab)*2.0*k));
        th3[k] = (float)((k+A-1.0)*(k+B-1.0)*(2.0*k+ab)/(k*(ab+k)*(2.0*k+ab-2.0)));
    }

    const int total = NALL * DIM;
    dim3 blk(256);
    dim3 grdE((total + 255) / 256);
    dim3 grdBin((NE + CHUNK - 1) / CHUNK);             // 1172
    dim3 grdBuck(NBUCK);                               // 1172
    dim3 grdRow((NALL * 64 + 255) / 256);              // wave-per-row

    if (ws_size >= need) {
        // ---- CSR build: coarse LDS-binned bucketing, then exact in-bucket sort ----
        hipMemsetAsync(bcnt, 0, NBUCK * sizeof(int), stream);
        hipMemsetAsync(bfill, 0, NBUCK * sizeof(int), stream);
        bucket_hist_kernel<<<grdBin, blk, 0, stream>>>(rows, bcnt);
        bucket_scan_kernel<<<1, 1024, 0, stream>>>(bcnt, bptr);
        binned_scatter_kernel<<<grdBin, blk, 0, stream>>>(rows, cols, vals, bptr, bfill, tmp);
        bucket_sort_kernel<<<grdBuck, blk, 0, stream>>>(bptr, tmp, sedges, row_ptr);

        // ---- propagation ----
        concat_init_kernel<<<grdE, blk, 0, stream>>>(user_emb, item_emb, W0, out);
        spmm_combine_kernel<<<grdRow, blk, 0, stream>>>(row_ptr, sedges, W0, W0, W0,
                                                        c1, c0, 0.0f, W1, out);
        spmm_combine_kernel<<<grdRow, blk, 0, stream>>>(row_ptr, sedges, W1, W1, W0,
                                                        th1[2], th2[2], th3[2], W2, out);
        spmm_combine_kernel<<<grdRow, blk, 0, stream>>>(row_ptr, sedges, W2, W2, W1,
                                                        th1[3], th2[3], th3[3], W0, out);
        finalize_kernel<<<grdE, blk, 0, stream>>>(user_emb, item_emb, out);
    } else {
        // ---- fallback: atomic path ----
        long long spmm_threads = (long long)NE * 64;
        dim3 grdS((unsigned)((spmm_threads + 255) / 256));
        concat_init_kernel<<<grdE, blk, 0, stream>>>(user_emb, item_emb, W0, out);
        hipMemsetAsync(W1, 0, nbuf * sizeof(float), stream);
        spmm_atomic_kernel<<<grdS, blk, 0, stream>>>(rows, cols, vals, W0, W1);
        combine3_kernel<<<grdE, blk, 0, stream>>>(W1, W0, W0, c1, c0, 0.0f, out);
        hipMemsetAsync(W2, 0, nbuf * sizeof(float), stream);
        spmm_atomic_kernel<<<grdS, blk, 0, stream>>>(rows, cols, vals, W1, W2);
        combine3_kernel<<<grdE, blk, 0, stream>>>(W2, W1, W0, th1[2], th2[2], th3[2], out);
        hipMemsetAsync(W0, 0, nbuf * sizeof(float), stream);
        spmm_atomic_kernel<<<grdS, blk, 0, stream>>>(rows, cols, vals, W2, W0);
        combine3_kernel<<<grdE, blk, 0, stream>>>(W0, W2, W1, th1[3], th2[3], th3[3], out);
        finalize_kernel<<<grdE, blk, 0, stream>>>(user_emb, item_emb, out);
    }
}